// Round 7
// baseline (34.599 us; speedup 1.0000x reference)
//
#include <hip/hip_runtime.h>
#include <math.h>

// ListNet segment-softmax CE, sorted week indices.
// BATCH = 4194304, NUM_WEEKS = 262144, avg 16 items/week.
//
// Per-week loss = T/S_l - log(S_s);  S_l = sum e^l, S_s = sum e^s, T = sum e^l*s.
// (eps inside log dropped; validated rounds 2-6, absmax 0.0)
//
// Round-7: r6 staging fixed per post-mortem:
//  - global_load_lds (async HBM->LDS, no VGPR roundtrip, no ds_write)
//  - ONE load phase per block, all 6 staging instrs issued up-front -> full
//    MLP, 2 barriers total (r6 had 2 serialized phases + reg roundtrip)
//  - T21 both-sides swizzle: LDS dest linear (HW requirement), global SOURCE
//    address pre-swizzled with involution p(s)=s^((s>>3)&7) on f4 slots; walk
//    reads stg[swz(2t+k)] -> all 8 bank-quads per 8 lanes, no conflicts.
//    p stays within 1KB granules -> global coalescing preserved.
//  - serial 8-item walk per thread (r5): interior runs finalized in regs,
//    head/tail runs -> LDS slot atomics, interior slots finalized per block.

#define TPB 256
#define CHUNK 2048        // items per block
#define CF4 512           // float4 slots per array per block
#define SLOTS 512         // max week-span+1 (~128 expected; 100+ sigma margin)

__device__ __forceinline__ int swz(int s) { return s ^ ((s >> 3) & 7); }

typedef __attribute__((address_space(1))) const void gvoid_t;
typedef __attribute__((address_space(3))) void ldsvoid_t;
__device__ __forceinline__ void gload16(const void* g, void* l) {
    __builtin_amdgcn_global_load_lds((gvoid_t*)g, (ldsvoid_t*)l, 16, 0, 0);
}

__device__ __forceinline__ void lds_flush(float* lel, float* les, float* ltl,
                                          int* lcnt, int s, float a, float b,
                                          float t, int c) {
    atomicAdd(&lel[s], a);
    atomicAdd(&les[s], b);
    atomicAdd(&ltl[s], t);
    atomicAdd(&lcnt[s], c);
}

__global__ __launch_bounds__(TPB) void main_pass(
        const float* __restrict__ scores, const float* __restrict__ labels,
        const int* __restrict__ widx,
        int* __restrict__ rec_week, float* __restrict__ rec_el,
        float* __restrict__ rec_es, float* __restrict__ rec_tl,
        int* __restrict__ rec_cnt,
        float* __restrict__ part_loss, int* __restrict__ part_nv) {
    __shared__ int4   stg_w[CF4];
    __shared__ float4 stg_l[CF4];
    __shared__ float4 stg_s[CF4];
    __shared__ float lel[SLOTS], les[SLOTS], ltl[SLOTS];
    __shared__ int lcnt[SLOTS];
    const int tid = threadIdx.x;
    const int lane = tid & 63, wid = tid >> 6;
    const int base = blockIdx.x * CHUNK;

    // issue ALL staging loads first (async, stay in flight while we init)
    const int4*   gw = reinterpret_cast<const int4*>(widx + base);
    const float4* gl = reinterpret_cast<const float4*>(labels + base);
    const float4* gs = reinterpret_cast<const float4*>(scores + base);
    #pragma unroll
    for (int j = 0; j < 2; ++j) {
        const int sb = wid * 128 + j * 64;     // wave-uniform LDS slot base
        const int g  = swz(sb + lane);         // per-lane pre-swizzled source
        gload16(gw + g, &stg_w[sb]);
        gload16(gl + g, &stg_l[sb]);
        gload16(gs + g, &stg_s[sb]);
    }
    for (int s = tid; s < SLOTS; s += TPB) {
        lel[s] = 0.f; les[s] = 0.f; ltl[s] = 0.f; lcnt[s] = 0;
    }
    __syncthreads();   // drains vmcnt(0): staging complete

    // stg[slot] holds global f4 slot swz(slot); global slot s is at stg[swz(s)]
    const int w0 = stg_w[0].x;                 // swz(0) == 0
    const int wl = stg_w[swz(CF4 - 1)].w;

    const int p0 = swz(2 * tid), p1 = swz(2 * tid + 1);
    const int4   wA = stg_w[p0], wB = stg_w[p1];
    const float4 lA = stg_l[p0], lB = stg_l[p1];
    const float4 sA = stg_s[p0], sB = stg_s[p1];

    float loss = 0.f; int nv = 0;
    int cw; float ra, rb, rt; int rc;
    bool head_saved = false;
    int hs = 0; float ha = 0.f, hb = 0.f, ht = 0.f; int hc = 0;
    {
        const float el = __expf(lA.x), es = __expf(sA.x);
        cw = wA.x; ra = el; rb = es; rt = el * sA.x; rc = 1;
    }
#define ITEM(wv, lv, sv)                                                       \
    {                                                                          \
        const float el = __expf(lv), es = __expf(sv);                          \
        if ((wv) == cw) { ra += el; rb += es; rt += el * (sv); ++rc; }         \
        else {                                                                 \
            if (!head_saved) {                                                 \
                hs = cw - w0; ha = ra; hb = rb; ht = rt; hc = rc;              \
                head_saved = true;                                             \
            } else if (rc >= 2) {                                              \
                loss += rt / ra - __logf(rb); ++nv;  /* thread-complete week */\
            }                                                                  \
            cw = (wv); ra = el; rb = es; rt = el * (sv); rc = 1;               \
        }                                                                      \
    }
    ITEM(wA.y, lA.y, sA.y) ITEM(wA.z, lA.z, sA.z) ITEM(wA.w, lA.w, sA.w)
    ITEM(wB.x, lB.x, sB.x) ITEM(wB.y, lB.y, sB.y) ITEM(wB.z, lB.z, sB.z)
    ITEM(wB.w, lB.w, sB.w)
#undef ITEM
    if (head_saved) lds_flush(lel, les, ltl, lcnt, hs, ha, hb, ht, hc);
    lds_flush(lel, les, ltl, lcnt, cw - w0, ra, rb, rt, rc);
    __syncthreads();

    // block-interior slots (strictly between w0 and wl) are complete here
    const int span = wl - w0;
    for (int s = 1 + tid; s < span; s += TPB) {
        const int c = lcnt[s];
        if (c >= 2) { loss += ltl[s] / lel[s] - __logf(les[s]); ++nv; }
    }
    #pragma unroll
    for (int off = 32; off; off >>= 1) {
        loss += __shfl_down(loss, off);
        nv   += __shfl_down(nv, off);
    }
    __shared__ float ra4[4];
    __shared__ int   rn4[4];
    if (lane == 0) { ra4[wid] = loss; rn4[wid] = nv; }
    __syncthreads();
    if (tid == 0) {
        part_loss[blockIdx.x] = ra4[0] + ra4[1] + ra4[2] + ra4[3];
        part_nv[blockIdx.x]   = rn4[0] + rn4[1] + rn4[2] + rn4[3];
        const int b2 = blockIdx.x * 2;
        rec_week[b2] = w0;
        rec_el[b2] = lel[0]; rec_es[b2] = les[0];
        rec_tl[b2] = ltl[0]; rec_cnt[b2] = lcnt[0];
        rec_week[b2 + 1] = wl;
        if (span > 0) {
            rec_el[b2 + 1] = lel[span]; rec_es[b2 + 1] = les[span];
            rec_tl[b2 + 1] = ltl[span]; rec_cnt[b2 + 1] = lcnt[span];
        } else {  // single-week block: zero filler keeps run-adjacency intact
            rec_el[b2 + 1] = 0.f; rec_es[b2 + 1] = 0.f;
            rec_tl[b2 + 1] = 0.f; rec_cnt[b2 + 1] = 0;
        }
    }
}

__global__ __launch_bounds__(1024) void finalize(
        const int* __restrict__ rec_week, const float* __restrict__ rec_el,
        const float* __restrict__ rec_es, const float* __restrict__ rec_tl,
        const int* __restrict__ rec_cnt,
        const float* __restrict__ part_loss, const int* __restrict__ part_nv,
        int nrec, int nb, float* __restrict__ out) {
    const int tid = threadIdx.x;
    float loss = 0.f; int nv = 0;
    for (int j = tid; j < nrec; j += 1024) {
        const int w = rec_week[j];
        if (j > 0 && rec_week[j - 1] == w) continue;  // not a run head
        float a = rec_el[j], b = rec_es[j], t = rec_tl[j];
        int c = rec_cnt[j];
        int k = j + 1;
        while (k < nrec && rec_week[k] == w) {
            a += rec_el[k]; b += rec_es[k]; t += rec_tl[k]; c += rec_cnt[k]; ++k;
        }
        if (c >= 2) { loss += t / a - __logf(b); ++nv; }
    }
    for (int j = tid; j < nb; j += 1024) { loss += part_loss[j]; nv += part_nv[j]; }
    #pragma unroll
    for (int off = 32; off; off >>= 1) {
        loss += __shfl_down(loss, off);
        nv   += __shfl_down(nv, off);
    }
    __shared__ float ra[16];
    __shared__ int   rn[16];
    const int lane = tid & 63, wv = tid >> 6;
    if (lane == 0) { ra[wv] = loss; rn[wv] = nv; }
    __syncthreads();
    if (tid == 0) {
        float tl = 0.f; int tn = 0;
        for (int k = 0; k < 16; ++k) { tl += ra[k]; tn += rn[k]; }
        out[0] = (tn > 0) ? (-tl / (float)tn) : 0.f;
    }
}

extern "C" void kernel_launch(void* const* d_in, const int* in_sizes, int n_in,
                              void* d_out, int out_size, void* d_ws, size_t ws_size,
                              hipStream_t stream) {
    const float* scores = (const float*)d_in[0];
    const float* labels = (const float*)d_in[1];
    const int*   widx   = (const int*)d_in[2];
    const int n  = in_sizes[0];
    const int nb = n / CHUNK;      // 2048
    const int nrec = nb * 2;

    char* ws = (char*)d_ws;
    size_t off = 0;
    int*   rec_week = (int*)  (ws + off); off += (size_t)nrec * 4;
    float* rec_el   = (float*)(ws + off); off += (size_t)nrec * 4;
    float* rec_es   = (float*)(ws + off); off += (size_t)nrec * 4;
    float* rec_tl   = (float*)(ws + off); off += (size_t)nrec * 4;
    int*   rec_cnt  = (int*)  (ws + off); off += (size_t)nrec * 4;
    float* part_loss= (float*)(ws + off); off += (size_t)nb * 4;
    int*   part_nv  = (int*)  (ws + off);

    float* out = (float*)d_out;

    main_pass<<<nb, TPB, 0, stream>>>(scores, labels, widx,
                                      rec_week, rec_el, rec_es, rec_tl, rec_cnt,
                                      part_loss, part_nv);
    finalize<<<1, 1024, 0, stream>>>(rec_week, rec_el, rec_es, rec_tl, rec_cnt,
                                     part_loss, part_nv, nrec, nb, out);
}